// Round 6
// baseline (558.743 us; speedup 1.0000x reference)
//
#include <hip/hip_runtime.h>
#include <cmath>

typedef __attribute__((ext_vector_type(8))) short bf16x8;
typedef __attribute__((ext_vector_type(4))) float f32x4;
typedef __attribute__((ext_vector_type(16))) float f32x16;
typedef unsigned short u16;

struct __align__(8) us4 { u16 x, y, z, w; };

__device__ __forceinline__ u16 f2bf(float f) {
    union { float f; unsigned u; } v; v.f = f;
    unsigned u = v.u;
    u += 0x7fffu + ((u >> 16) & 1u);   // RNE
    return (u16)(u >> 16);
}
__device__ __forceinline__ float bf2f(u16 h) {
    union { unsigned u; float f; } v; v.u = ((unsigned)h) << 16;
    return v.f;
}
__device__ __forceinline__ f32x16 mfma32(bf16x8 a, bf16x8 b, f32x16 c) {
    return __builtin_amdgcn_mfma_f32_32x32x16_bf16(a, b, c, 0, 0, 0);
}
__device__ __forceinline__ void ld_lds16(const u16* g, u16* l) {
    __builtin_amdgcn_global_load_lds(
        (const __attribute__((address_space(1))) unsigned int*)g,
        (__attribute__((address_space(3))) unsigned int*)l, 16, 0, 0);
}

// ---------------- x -> CatA right half (bf16) ----------------
__global__ __launch_bounds__(256) void cvtx(const float* __restrict__ in,
                                            u16* __restrict__ CatA) {
    int i = blockIdx.x * 256 + threadIdx.x;         // over 3145728 float4 groups
    float4 f = reinterpret_cast<const float4*>(in)[i];
    us4 o; o.x = f2bf(f.x); o.y = f2bf(f.y); o.z = f2bf(f.z); o.w = f2bf(f.w);
    int row = i / 192, col = (i % 192) * 4;
    *reinterpret_cast<us4*>(CatA + (size_t)row * 1536 + 768 + col) = o;
}

// ---------------- 7 weight converts in one dispatch ----------------
struct WCvt { const float* s[7]; u16* d[7]; int ld[7]; };
__global__ __launch_bounds__(256) void cvtw(WCvt w) {
    int wi = blockIdx.y;
    int i = blockIdx.x * 256 + threadIdx.x;         // over 147456 float4 groups
    float4 f = reinterpret_cast<const float4*>(w.s[wi])[i];
    us4 o; o.x = f2bf(f.x); o.y = f2bf(f.y); o.z = f2bf(f.z); o.w = f2bf(f.w);
    int row = i / 192, col = (i % 192) * 4;
    *reinterpret_cast<us4*>(w.d[wi] + (size_t)row * w.ld[wi] + col) = o;
}

// ---------------- w' = wq @ Wfc (fp32), + scalar wq.b_fc ----------------
__global__ __launch_bounds__(256) void wprep(const float* __restrict__ Wfc,
                                             const float* __restrict__ wq,
                                             const float* __restrict__ wk,
                                             const float* __restrict__ bfc,
                                             float* __restrict__ wqp, float* __restrict__ wkp,
                                             float* __restrict__ qks) {
    if (blockIdx.x < 3) {
        int d = blockIdx.x * 256 + threadIdx.x;
        float sq = 0.f, sk = 0.f;
        for (int e = 0; e < 768; e++) {
            float v = Wfc[(size_t)e * 768 + d];
            sq = fmaf(wq[e], v, sq); sk = fmaf(wk[e], v, sk);
        }
        wqp[d] = sq; wkp[d] = sk;
    } else if (threadIdx.x < 64) {
        float sq = 0.f, sk = 0.f;
        for (int e = threadIdx.x; e < 768; e += 64) {
            sq = fmaf(wq[e], bfc[e], sq); sk = fmaf(wk[e], bfc[e], sk);
        }
#pragma unroll
        for (int off = 32; off; off >>= 1) { sq += __shfl_xor(sq, off); sk += __shfl_xor(sk, off); }
        if (threadIdx.x == 0) { qks[0] = sq; qks[1] = sk; }
    }
}

// ---------------- q/k GEMV from bf16 x (CatA right half) ----------------
__global__ __launch_bounds__(256) void k_qk2(const u16* __restrict__ xb,
                                             const float* __restrict__ wqp,
                                             const float* __restrict__ wkp,
                                             const float* __restrict__ qks,
                                             float* __restrict__ qv, float* __restrict__ kv) {
    int m = blockIdx.x * 256 + threadIdx.x;
    const u16* row = xb + (size_t)m * 1536;
    float sq = 0.f, sk = 0.f;
    for (int d = 0; d < 768; d += 8) {
        bf16x8 xv = *reinterpret_cast<const bf16x8*>(row + d);
#pragma unroll
        for (int t = 0; t < 8; t++) {
            float f = bf2f((u16)xv[t]);
            sq = fmaf(f, wqp[d + t], sq); sk = fmaf(f, wkp[d + t], sk);
        }
    }
    qv[m] = sq + qks[0];
    kv[m] = sk + qks[1];
}

// =====================================================================
// GEMM core: 128x128 tile, BK=64, global_load_lds w16, XOR-by-(row&7)
// chunk swizzle (0 conflicts measured r5), MFMA 32x32x16 (m119: +20%
// ceiling vs 16x16x32, half the MFMA instruction count).
// Per wave: 64x64 out = 2x2 tiles of 32x32, acc = 2x2 x f32x16 (64 AGPR).
// C/D map (m74/m101): col=lane&31, row=(reg&3)+8*(reg>>2)+4*(lane>>5).
// =====================================================================
enum { EPI_FPT = 0, EPI_Y, EPI_GATES, EPI_OUT };

struct Epi {
    const float* b1; const float* b2; const float* b3; const float* b4;
    u16* fpT;
    u16* catA;                                                 // Y
    const u16* xb;        // CatA+768 (stride 1536)
    u16* ub_o; u16* rxb_o;                                     // GATES
    const u16* ub; float* of;                                  // OUT
};

template<int EPI, int PH>
__global__ __launch_bounds__(256) void g128(
    const u16* __restrict__ A1, const u16* __restrict__ B1,
    const u16* __restrict__ A2, const u16* __restrict__ B2,
    int K, int ldA1, int ldB1, int ldA2, int ldB2,
    size_t zA, size_t zB, Epi e)
{
    __shared__ u16 lA[128 * 64];
    __shared__ u16 lB[128 * 64];

    const int t = threadIdx.x;
    const int w = t >> 6, lane = t & 63;
    const int l31 = lane & 31, h = lane >> 5, l7 = lane & 7;
    const int row0 = blockIdx.x * 128;
    int col0, grp = 0;
    if constexpr (EPI == EPI_GATES) { grp = blockIdx.y / 6; col0 = (blockIdx.y % 6) * 128; }
    else col0 = blockIdx.y * 128;

    // staging: linear chunk-id = q*256 + t -> LDS offset *16B (wave-uniform
    // base + lane*16). Global: row = q*32 + (t>>3), chunk = (t&7)^(row&7).
    const int rs2 = t >> 3;
    const int kc2 = (((t & 7) ^ (rs2 & 7)) * 8);
    u16* dA_[4]; u16* dB_[4];
#pragma unroll
    for (int q = 0; q < 4; q++) {
        dA_[q] = lA + q * 2048 + w * 512;
        dB_[q] = lB + q * 2048 + w * 512;
    }

    // compute map: wave (w&1) row-half, (w>>1) col-half; 2x2 of 32x32.
    // A-frag: row=lane&31, k=(lane>>5)*8+j ; sub-step s: logical chunk 2s+h,
    // stored at (2s+h)^(row&7), row&7 == l7.
    int aof[2][4], bof[2][4];
#pragma unroll
    for (int i = 0; i < 2; i++) {
        int rowA = (w & 1) * 64 + i * 32 + l31;
#pragma unroll
        for (int s = 0; s < 4; s++) aof[i][s] = rowA * 64 + (((2 * s + h) ^ l7) * 8);
    }
#pragma unroll
    for (int j = 0; j < 2; j++) {
        int colB = (w >> 1) * 64 + j * 32 + l31;
#pragma unroll
        for (int s = 0; s < 4; s++) bof[j][s] = colB * 64 + (((2 * s + h) ^ l7) * 8);
    }

    f32x16 acc[2][2] = {};
    bool first = true;

#pragma unroll
    for (int ph = 0; ph < PH; ph++) {
        const u16* As; const u16* Bs; int ldA, ldB;
        if (ph == 0) { As = A1 + (size_t)blockIdx.z * zA; Bs = B1 + (size_t)blockIdx.z * zB; ldA = ldA1; ldB = ldB1; }
        else         { As = A2; Bs = B2; ldA = ldA2; ldB = ldB2; }
        if constexpr (EPI == EPI_GATES) Bs += (size_t)grp * (768 * 1536);
        const u16* gA = As + (size_t)(row0 + rs2) * ldA + kc2;
        const u16* gB = Bs + (size_t)(col0 + rs2) * ldB + kc2;

        for (int k0 = 0; k0 < K; k0 += 64) {
            if (!first) __syncthreads();
            first = false;
#pragma unroll
            for (int q = 0; q < 4; q++) {
                ld_lds16(gA + (size_t)(q * 32) * ldA + k0, dA_[q]);
                ld_lds16(gB + (size_t)(q * 32) * ldB + k0, dB_[q]);
            }
            __syncthreads();

#pragma unroll
            for (int s = 0; s < 4; s++) {
                bf16x8 a0 = *reinterpret_cast<const bf16x8*>(lA + aof[0][s]);
                bf16x8 a1 = *reinterpret_cast<const bf16x8*>(lA + aof[1][s]);
                bf16x8 b0 = *reinterpret_cast<const bf16x8*>(lB + bof[0][s]);
                bf16x8 b1 = *reinterpret_cast<const bf16x8*>(lB + bof[1][s]);
                acc[0][0] = mfma32(a0, b0, acc[0][0]);
                acc[0][1] = mfma32(a0, b1, acc[0][1]);
                acc[1][0] = mfma32(a1, b0, acc[1][0]);
                acc[1][1] = mfma32(a1, b1, acc[1][1]);
            }
        }
    }

    // ---------------- epilogue ----------------
#pragma unroll
    for (int i = 0; i < 2; i++) {
        const int rb = row0 + (w & 1) * 64 + i * 32 + 4 * h;   // local row base
#pragma unroll
        for (int j = 0; j < 2; j++) {
            const int gc = col0 + (w >> 1) * 64 + j * 32 + l31;
            if constexpr (EPI == EPI_FPT) {
                float bias = e.b1[gc];
#pragma unroll
                for (int g = 0; g < 4; g++) {
                    int gr0 = rb + 8 * g;
                    int bb = gr0 >> 10, nn = gr0 & 1023;
                    us4 o;
                    o.x = f2bf(acc[i][j][4 * g + 0] + bias);
                    o.y = f2bf(acc[i][j][4 * g + 1] + bias);
                    o.z = f2bf(acc[i][j][4 * g + 2] + bias);
                    o.w = f2bf(acc[i][j][4 * g + 3] + bias);
                    *reinterpret_cast<us4*>(e.fpT + (size_t)bb * 786432 + (size_t)gc * 1024 + nn) = o;
                }
            } else if constexpr (EPI == EPI_Y) {
                size_t zb = (size_t)blockIdx.z * 1024;
#pragma unroll
                for (int g = 0; g < 4; g++)
#pragma unroll
                    for (int r = 0; r < 4; r++)
                        e.catA[(zb + rb + 8 * g + r) * 1536 + gc] = f2bf(acc[i][j][4 * g + r]);
            } else if constexpr (EPI == EPI_GATES) {
                if (grp == 0) {
                    float bias = e.b1[gc] + e.b2[gc];      // b_uy + b_ux
#pragma unroll
                    for (int g = 0; g < 4; g++)
#pragma unroll
                        for (int r = 0; r < 4; r++) {
                            size_t idx = (size_t)(rb + 8 * g + r) * 768 + gc;
                            e.ub_o[idx] = f2bf(1.f / (1.f + __expf(-(acc[i][j][4 * g + r] + bias))));
                        }
                } else {
                    float bias = e.b3[gc] + e.b4[gc];      // b_ry + b_rx
#pragma unroll
                    for (int g = 0; g < 4; g++)
#pragma unroll
                        for (int r = 0; r < 4; r++) {
                            size_t row = (size_t)(rb + 8 * g + r);
                            float rr = 1.f / (1.f + __expf(-(acc[i][j][4 * g + r] + bias)));
                            float xv = bf2f(e.xb[row * 1536 + gc]);
                            e.rxb_o[row * 768 + gc] = f2bf(rr * xv);
                        }
                }
            } else {  // EPI_OUT: acc = y@Wty + rx@Wtx
                float bias = e.b1[gc] + e.b2[gc];          // b_ty + b_tx
#pragma unroll
                for (int g = 0; g < 4; g++)
#pragma unroll
                    for (int r = 0; r < 4; r++) {
                        size_t row = (size_t)(rb + 8 * g + r);
                        float tt = tanhf(acc[i][j][4 * g + r] + bias);
                        float uu = bf2f(e.ub[row * 768 + gc]);
                        float xv = bf2f(e.xb[row * 1536 + gc]);
                        e.of[row * 768 + gc] = (1.f - uu) * xv + uu * tt;
                    }
            }
        }
    }
}

// ---------------- softmax: one wave per row, shuffle-only reductions ----------------
__global__ __launch_bounds__(256) void k_soft4(const float* __restrict__ adj,
                                               const float* __restrict__ qv,
                                               const float* __restrict__ kv,
                                               const float* __restrict__ bq,
                                               const float* __restrict__ bk,
                                               u16* __restrict__ attb) {
    int wv = threadIdx.x >> 6, lane = threadIdx.x & 63;
    int bn = blockIdx.x * 4 + wv;
    int b = bn >> 10;
    const float* adjrow = adj + (size_t)bn * 1024 + lane * 16;
    const float* krow = kv + (b << 10) + lane * 16;
    float q = qv[bn] + bq[0] + bk[0];

    float v[16];
#pragma unroll
    for (int c = 0; c < 4; c++) {
        float4 a4 = *reinterpret_cast<const float4*>(adjrow + c * 4);
        float4 k4 = *reinterpret_cast<const float4*>(krow + c * 4);
        float* vv = v + c * 4;
        vv[0] = q + k4.x + (1.f - a4.x) * -1.0e9f;
        vv[1] = q + k4.y + (1.f - a4.y) * -1.0e9f;
        vv[2] = q + k4.z + (1.f - a4.z) * -1.0e9f;
        vv[3] = q + k4.w + (1.f - a4.w) * -1.0e9f;
    }
#pragma unroll
    for (int t = 0; t < 16; t++) v[t] = v[t] >= 0.f ? v[t] : 0.01f * v[t];

    float mx = v[0];
#pragma unroll
    for (int t = 1; t < 16; t++) mx = fmaxf(mx, v[t]);
#pragma unroll
    for (int off = 32; off; off >>= 1) mx = fmaxf(mx, __shfl_xor(mx, off));

    float s = 0.f;
#pragma unroll
    for (int t = 0; t < 16; t++) { v[t] = __expf(v[t] - mx); s += v[t]; }
#pragma unroll
    for (int off = 32; off; off >>= 1) s += __shfl_xor(s, off);
    float inv = 1.f / s;

    u16* orow = attb + (size_t)bn * 1024 + lane * 16;
#pragma unroll
    for (int c = 0; c < 4; c++) {
        us4 o;
        o.x = f2bf(v[c * 4 + 0] * inv); o.y = f2bf(v[c * 4 + 1] * inv);
        o.z = f2bf(v[c * 4 + 2] * inv); o.w = f2bf(v[c * 4 + 3] * inv);
        *reinterpret_cast<us4*>(orow + c * 4) = o;
    }
}

extern "C" void kernel_launch(void* const* d_in, const int* in_sizes, int n_in,
                              void* d_out, int out_size, void* d_ws, size_t ws_size,
                              hipStream_t stream) {
    const float* x    = (const float*)d_in[0];
    const float* adj  = (const float*)d_in[1];
    const float* W_fc = (const float*)d_in[2];
    const float* b_fc = (const float*)d_in[3];
    const float* w_q  = (const float*)d_in[4];
    const float* b_q  = (const float*)d_in[5];
    const float* w_k  = (const float*)d_in[6];
    const float* b_k  = (const float*)d_in[7];
    const float* W_uy = (const float*)d_in[8];
    const float* b_uy = (const float*)d_in[9];
    const float* W_ux = (const float*)d_in[10];
    const float* b_ux = (const float*)d_in[11];
    const float* W_ry = (const float*)d_in[12];
    const float* b_ry = (const float*)d_in[13];
    const float* W_rx = (const float*)d_in[14];
    const float* b_rx = (const float*)d_in[15];
    const float* W_ty = (const float*)d_in[16];
    const float* b_ty = (const float*)d_in[17];
    const float* W_tx = (const float*)d_in[18];
    const float* b_tx = (const float*)d_in[19];

    char* ws = (char*)d_ws;
    u16*   CatA  = (u16*)  (ws + 0);            // 16384x1536 bf16  [y | x]   50331648
    u16*   Wfc_b = (u16*)  (ws + 50331648);     //  1179648
    u16*   Wty_b = (u16*)  (ws + 51511296);     //  1179648
    u16*   Wtx_b = (u16*)  (ws + 52690944);     //  1179648
    u16*   Wg    = (u16*)  (ws + 53870592);     // [ [Wuy|Wux] ; [Wry|Wrx] ] 4718592
    u16*   fpT   = (u16*)  (ws + 58589184);     // 16x768x1024 bf16          25165824
    float* qv    = (float*)(ws + 83755008);     // 16384 f32
    float* kv    = (float*)(ws + 83820544);     // 16384 f32
    u16*   attb  = (u16*)  (ws + 83886080);     // 16x1024x1024 bf16         33554432
    u16*   u_b   = (u16*)  (ws + 83886080);     // alias attb (dead after av)
    u16*   rxb   = (u16*)  (ws + 117440512);    // 16384x768 bf16            25165824
    float* wqp   = (float*)(ws + 142606336);    // 768 f32
    float* wkp   = (float*)(ws + 142609408);    // 768 f32
    float* qks   = (float*)(ws + 142612480);    // 2 f32

    cvtx<<<12288, 256, 0, stream>>>(x, CatA);

    WCvt wc;
    wc.s[0] = W_fc; wc.d[0] = Wfc_b;              wc.ld[0] = 768;
    wc.s[1] = W_ty; wc.d[1] = Wty_b;              wc.ld[1] = 768;
    wc.s[2] = W_tx; wc.d[2] = Wtx_b;              wc.ld[2] = 768;
    wc.s[3] = W_uy; wc.d[3] = Wg;                 wc.ld[3] = 1536;
    wc.s[4] = W_ux; wc.d[4] = Wg + 768;           wc.ld[4] = 1536;
    wc.s[5] = W_ry; wc.d[5] = Wg + 768 * 1536;    wc.ld[5] = 1536;
    wc.s[6] = W_rx; wc.d[6] = Wg + 768 * 1536 + 768; wc.ld[6] = 1536;
    cvtw<<<dim3(576, 7), 256, 0, stream>>>(wc);

    wprep<<<4, 256, 0, stream>>>(W_fc, w_q, w_k, b_fc, wqp, wkp, qks);
    k_qk2<<<64, 256, 0, stream>>>(CatA + 768, wqp, wkp, qks, qv, kv);
    k_soft4<<<4096, 256, 0, stream>>>(adj, qv, kv, b_q, b_k, attb);

    Epi e{};
    // feat_proj = x @ Wfc^T + b (A = CatA right half), stored transposed
    e = Epi{}; e.b1 = b_fc; e.fpT = fpT;
    g128<EPI_FPT, 1><<<dim3(128, 6), 256, 0, stream>>>(CatA + 768, Wfc_b, nullptr, nullptr,
                                                       768, 1536, 768, 0, 0, 0, 0, e);
    // y = att @ fp  -> CatA left half
    e = Epi{}; e.catA = CatA;
    g128<EPI_Y, 1><<<dim3(8, 6, 16), 256, 0, stream>>>(attb, fpT, nullptr, nullptr,
                                                       1024, 1024, 1024, 0, 0,
                                                       1048576, 786432, e);
    // gates: [u | r] = CatA @ [Wuy|Wux ; Wry|Wrx]^T
    e = Epi{}; e.b1 = b_uy; e.b2 = b_ux; e.b3 = b_ry; e.b4 = b_rx;
    e.xb = CatA + 768; e.ub_o = u_b; e.rxb_o = rxb;
    g128<EPI_GATES, 1><<<dim3(128, 12), 256, 0, stream>>>(CatA, Wg, nullptr, nullptr,
                                                          1536, 1536, 1536, 0, 0, 0, 0, e);
    // out = (1-u)x + u*tanh(y@Wty^T + rx@Wtx^T + b_ty + b_tx)
    e = Epi{}; e.b1 = b_ty; e.b2 = b_tx; e.ub = u_b; e.xb = CatA + 768; e.of = (float*)d_out;
    g128<EPI_OUT, 2><<<dim3(128, 6), 256, 0, stream>>>(CatA, Wty_b, rxb, Wtx_b,
                                                       768, 1536, 768, 768, 768, 0, 0, e);
}